// Round 1
// baseline (181.288 us; speedup 1.0000x reference)
//
#include <hip/hip_runtime.h>
#include <hip/hip_bf16.h>

#define NS 8192
#define NQ 8192
#define NTOT 16384
#define KDIM 1024
#define ED 512
#define NC 64
#define PBLK 64   // proto partial row-chunks along support dim

typedef __attribute__((ext_vector_type(4))) float fx4;
typedef __attribute__((ext_vector_type(4))) int ix4;
typedef __attribute__((ext_vector_type(8))) short sx8;
typedef __attribute__((ext_vector_type(4))) unsigned short ux4;
typedef __attribute__((ext_vector_type(8))) unsigned short ux8;

__device__ __forceinline__ unsigned short f2bf(float f) {
  union { float f; unsigned u; } v; v.f = f;
  unsigned r = v.u + 0x7fffu + ((v.u >> 16) & 1u);   // RNE
  return (unsigned short)(r >> 16);
}
__device__ __forceinline__ float bf2f(unsigned short h) {
  union { unsigned u; float f; } v; v.u = ((unsigned)h) << 16;
  return v.f;
}

// async global->LDS DMA, 16 B per lane. LDS dest = wave-uniform base + lane*16.
__device__ __forceinline__ void async_ld16(const void* g, void* l) {
  __builtin_amdgcn_global_load_lds(
      (const __attribute__((address_space(1))) unsigned int*)g,
      (__attribute__((address_space(3))) unsigned int*)l, 16, 0, 0);
}

// ---------------------------------------------------------------------------
// K0: W -> Wt bf16 (B^T), 512 blocks; also zeroes rowssq (32 floats/block).
// X conversion is now fused into K1 (saves ~100 MB of HBM traffic:
// 33.5 MB Xbf write + 33.5 MB Xbf re-read, and X fp32 is read once not twice).
// ---------------------------------------------------------------------------
__global__ __launch_bounds__(256) void k_prep(
    const float* __restrict__ W, unsigned short* __restrict__ Wt,
    float* __restrict__ rowssq) {
  __shared__ float tile[32][33];
  int bid = blockIdx.x;            // 0..511
  int t = threadIdx.x;
  int k0 = (bid & 31) * 32;
  int n0 = (bid >> 5) * 32;
  int tx = t & 31, ty = t >> 5;
#pragma unroll
  for (int i = ty; i < 32; i += 8)
    tile[i][tx] = W[(size_t)(k0 + i) * ED + n0 + tx];
  __syncthreads();
#pragma unroll
  for (int i = ty; i < 32; i += 8)
    Wt[(size_t)(n0 + i) * KDIM + k0 + tx] = f2bf(tile[tx][i]);
  if (t < 32) rowssq[bid * 32 + t] = 0.f;
}

// ---------------------------------------------------------------------------
// K1: emb = bf16(X) @ W + per-row ssq partials, X read directly as fp32.
// Tile 128Mx128N, BK=64, grid 512 (2 blocks/CU, LDS 64 KB). Waves 2x2,
// each 64x64: 16 ds_read_b128 feed 32 MFMA per iter.
// A path: reg-staged (global fp32 fx4 x2 -> RNE cvt -> swizzled ds_write_b128),
//   T14 split: loads issued BEFORE the MFMA block, cvt+write AFTER it, so
//   HBM latency hides under 32 MFMAs.
// B path: global_load_lds(16B), double-buffered, global-side XOR swizzle
//   (slot = kq^(row&7)): DMA writes lane-linear, fragment reads 2-way (free).
// LDS contents identical to the previous Xbf-DMA version (same swizzle, same
// RNE rounding) -> fragment-read side unchanged.
// ---------------------------------------------------------------------------
__global__ __launch_bounds__(256) void k_gemm_embed(
    const float* __restrict__ Xs, const float* __restrict__ Xq,
    const unsigned short* __restrict__ Wt,
    unsigned short* __restrict__ emb, float* __restrict__ rowssq) {
  __shared__ unsigned short Ash[2][128 * 8 * 8];  // 16 KB per buf, [m*8+slot][8]
  __shared__ unsigned short Bsh[2][128 * 8 * 8];  // 16 KB per buf, [n*8+slot][8]

  int lid = blockIdx.x;            // 0..511
  int x = lid & 7;                 // xcd (dispatch round-robin heuristic)
  int s = lid >> 3;                // 0..63
  int m_blk = x * 16 + (s >> 2);   // 0..127
  int n_blk = s & 3;               // 0..3

  const float* Xsrc = (m_blk < 64)
      ? (Xs + (size_t)m_blk * 128 * KDIM)
      : (Xq + (size_t)(m_blk - 64) * 128 * KDIM);
  const unsigned short* Wrow = Wt + (size_t)n_blk * 128 * KDIM;

  int t = threadIdx.x;
  int lane = t & 63, w = t >> 6;
  int wm = w >> 1, wn = w & 1;
  int quad = lane >> 4, ml = lane & 15;

  fx4 acc[4][4];
#pragma unroll
  for (int i = 0; i < 4; ++i)
#pragma unroll
    for (int j = 0; j < 4; ++j) acc[i][j] = fx4{0.f, 0.f, 0.f, 0.f};

  fx4 av[4][2];   // staged A fp32: 4 chunks x 8 floats, live across MFMA block

  auto loadA = [&](int kt) {
    int k0 = kt * 64;
#pragma unroll
    for (int c = 0; c < 4; ++c) {            // A: 1024 chunks of 8, 4/thread
      int ch = t + 256 * c;
      int m = ch >> 3, kq = ch & 7;          // kq = GLOBAL k-octet
      const float* g = &Xsrc[(size_t)m * KDIM + k0 + kq * 8];
      av[c][0] = *(const fx4*)g;
      av[c][1] = *(const fx4*)(g + 4);
    }
  };
  auto writeA = [&](int b) {
#pragma unroll
    for (int c = 0; c < 4; ++c) {
      int ch = t + 256 * c;
      int m = ch >> 3, kq = ch & 7;
      ux8 o;
      o[0] = f2bf(av[c][0].x); o[1] = f2bf(av[c][0].y);
      o[2] = f2bf(av[c][0].z); o[3] = f2bf(av[c][0].w);
      o[4] = f2bf(av[c][1].x); o[5] = f2bf(av[c][1].y);
      o[6] = f2bf(av[c][1].z); o[7] = f2bf(av[c][1].w);
      // global kq lands in slot kq^(m&7): identical layout to old DMA path
      *(ux8*)&Ash[b][((m * 8) + (kq ^ (m & 7))) * 8] = o;
    }
  };
  auto stageB = [&](int kt, int b) {
    int k0 = kt * 64;
#pragma unroll
    for (int c = 0; c < 4; ++c) {            // B: 1024 chunks, 4/thread
      int ch = t + 256 * c;
      int n = ch >> 3;
      int kq = (ch & 7) ^ (n & 7);           // global-side swizzle
      async_ld16(&Wrow[(size_t)n * KDIM + k0 + kq * 8],
                 &Bsh[b][(w * 64 + 256 * c) * 8]);
    }
  };

  loadA(0);
  stageB(0, 0);
  writeA(0);
  for (int kt = 0; kt < 16; ++kt) {
    int b = kt & 1;
    __syncthreads();                 // drains DMA + ds_writes for buf b
    if (kt < 15) { loadA(kt + 1); stageB(kt + 1, b ^ 1); }
#pragma unroll
    for (int s2 = 0; s2 < 2; ++s2) {
      int kq = s2 * 4 + quad;
      sx8 af[4], bfr[4];
#pragma unroll
      for (int i = 0; i < 4; ++i) {
        int row = wm * 64 + i * 16 + ml;
        af[i] = *(const sx8*)&Ash[b][(row * 8 + (kq ^ (row & 7))) * 8];
      }
#pragma unroll
      for (int j = 0; j < 4; ++j) {
        int nrow = wn * 64 + j * 16 + ml;
        bfr[j] = *(const sx8*)&Bsh[b][(nrow * 8 + (kq ^ (nrow & 7))) * 8];
      }
#pragma unroll
      for (int i = 0; i < 4; ++i)
#pragma unroll
        for (int j = 0; j < 4; ++j)
          acc[i][j] = __builtin_amdgcn_mfma_f32_16x16x32_bf16(af[i], bfr[j], acc[i][j], 0, 0, 0);
    }
    if (kt < 15) writeA(b ^ 1);      // cvt + ds_write after MFMAs (T14 split)
  }

  // epilogue: emb store + row-ssq partial (shfl width-16 + 1 atomic per row)
  int grow = m_blk * 128 + wm * 64;
  int gcol = n_blk * 128 + wn * 64;
#pragma unroll
  for (int i = 0; i < 4; ++i) {
#pragma unroll
    for (int r = 0; r < 4; ++r) {
      int mrow = grow + i * 16 + quad * 4 + r;
      float p = 0.f;
#pragma unroll
      for (int j = 0; j < 4; ++j) {
        emb[(size_t)mrow * ED + gcol + j * 16 + ml] = f2bf(acc[i][j][r]);
        p += acc[i][j][r] * acc[i][j][r];
      }
#pragma unroll
      for (int off = 1; off < 16; off <<= 1) p += __shfl_xor(p, off, 16);
      if (ml == 0) atomicAdd(&rowssq[mrow], p);
    }
  }
}

// ---------------------------------------------------------------------------
// K2: per-class partial sums of (emb_s / ||s||), LDS-accumulated.
// Grid (64 chunks, 8 dim-slices) = 512 blocks, 16 KB LDS [64c][64d],
// one lane-exclusive atomic per row (2-way banks = free).
// ---------------------------------------------------------------------------
__global__ __launch_bounds__(256) void k_proto_partial(
    const unsigned short* __restrict__ embS, const float* __restrict__ rowssq,
    const int* __restrict__ labels, float* __restrict__ Ppart) {
  __shared__ float Pl[NC * 64];  // 16 KB: [class][dim-within-slice]
  int t = threadIdx.x;
#pragma unroll
  for (int i = 0; i < 16; ++i) Pl[i * 256 + t] = 0.f;
  __syncthreads();

  int w = t >> 6, lane = t & 63;
  int ds = blockIdx.y;            // dim slice: dims [ds*64, ds*64+64)
  int row0 = blockIdx.x * (NS / PBLK);
#pragma unroll 4
  for (int r = w; r < NS / PBLK; r += 4) {
    int row = row0 + r;
    int lbl = labels[row];
    float scale = 1.0f / fmaxf(sqrtf(rowssq[row]), 1e-12f);
    float v = bf2f(embS[(size_t)row * ED + ds * 64 + lane]) * scale;
    atomicAdd(&Pl[lbl * 64 + lane], v);
  }
  __syncthreads();

  float* o = Ppart + (size_t)blockIdx.x * NC * ED + ds * 64;
#pragma unroll
  for (int i = 0; i < 16; ++i) {
    int idx = i * 256 + t;
    o[(size_t)(idx >> 6) * ED + (idx & 63)] = Pl[idx];
  }
}

// ---------------------------------------------------------------------------
// K3: reduce PBLK partials -> Pbf (bf16, MFMA B-fragment layout [kq][n][8]).
// ---------------------------------------------------------------------------
__global__ __launch_bounds__(256) void k_proto_reduce(
    const float* __restrict__ Ppart, unsigned short* __restrict__ Pbf) {
  int idx = blockIdx.x * 256 + threadIdx.x;  // 0..NC*ED-1
  int kq = idx >> 9;
  int n = (idx >> 3) & 63;
  int j = idx & 7;
  int d = kq * 8 + j;
  float s = 0.f;
#pragma unroll 8
  for (int b = 0; b < PBLK; ++b) s += Ppart[(size_t)b * NC * ED + n * ED + d];
  Pbf[idx] = f2bf(s);
}

// ---------------------------------------------------------------------------
// K4: class_scores = (emb_q @ P^T) / ||q|| + fused softmax.
// 512 single-wave blocks, 16 queries each; B-fragments from L2-hot Pbf.
// ---------------------------------------------------------------------------
__global__ __launch_bounds__(64) void k_scores(
    const unsigned short* __restrict__ embQ, const float* __restrict__ ssqQ,
    const unsigned short* __restrict__ Pbf, float* __restrict__ out) {
  int lane = threadIdx.x;
  int quad = lane >> 4, ml = lane & 15;
  int qrow0 = blockIdx.x * 16;

  fx4 acc[4];
#pragma unroll
  for (int i = 0; i < 4; ++i) acc[i] = fx4{0.f, 0.f, 0.f, 0.f};

#pragma unroll 4
  for (int ki = 0; ki < 16; ++ki) {
    sx8 a = *(const sx8*)&embQ[(size_t)(qrow0 + ml) * ED + ki * 32 + quad * 8];
#pragma unroll
    for (int nt = 0; nt < 4; ++nt) {
      sx8 b = *(const sx8*)&Pbf[((ki * 4 + quad) * 64 + nt * 16 + ml) * 8];
      acc[nt] = __builtin_amdgcn_mfma_f32_16x16x32_bf16(a, b, acc[nt], 0, 0, 0);
    }
  }

#pragma unroll
  for (int r = 0; r < 4; ++r) {
    int qq = qrow0 + quad * 4 + r;
    float scale = 1.0f / fmaxf(sqrtf(ssqQ[qq]), 1e-12f);
    float s[4];
#pragma unroll
    for (int nt = 0; nt < 4; ++nt) s[nt] = acc[nt][r] * scale;
    float m = fmaxf(fmaxf(s[0], s[1]), fmaxf(s[2], s[3]));
#pragma unroll
    for (int off = 1; off < 16; off <<= 1) m = fmaxf(m, __shfl_xor(m, off, 16));
    float e[4], ssum = 0.f;
#pragma unroll
    for (int nt = 0; nt < 4; ++nt) { e[nt] = __expf(s[nt] - m); ssum += e[nt]; }
#pragma unroll
    for (int off = 1; off < 16; off <<= 1) ssum += __shfl_xor(ssum, off, 16);
    float inv = 1.0f / ssum;
#pragma unroll
    for (int nt = 0; nt < 4; ++nt)
      out[(size_t)qq * NC + nt * 16 + ml] = e[nt] * inv;
  }
}

// ---------------------------------------------------------------------------
extern "C" void kernel_launch(void* const* d_in, const int* in_sizes, int n_in,
                              void* d_out, int out_size, void* d_ws, size_t ws_size,
                              hipStream_t stream) {
  const float* Xs     = (const float*)d_in[0];  // support_data [8192,1024]
  const int*   labels = (const int*)d_in[1];    // support_labels [8192]
  const float* Xq     = (const float*)d_in[2];  // query_data [8192,1024]
  const float* W      = (const float*)d_in[3];  // W [1024,512]
  float* out = (float*)d_out;

  char* ws = (char*)d_ws;
  size_t off = 0;
  unsigned short* Wt  = (unsigned short*)(ws + off); off += (size_t)ED * KDIM * 2;    // 1 MB
  unsigned short* emb = (unsigned short*)(ws + off); off += (size_t)NTOT * ED * 2;    // 16 MB
  float* rowssq = (float*)(ws + off); off += (size_t)NTOT * 4;                        // 64 KB
  float* Ppart  = (float*)(ws + off); off += (size_t)PBLK * NC * ED * 4;              // 8 MB
  unsigned short* Pbf = (unsigned short*)(ws + off); off += (size_t)NC * ED * 2;      // 64 KB

  k_prep<<<512, 256, 0, stream>>>(W, Wt, rowssq);
  k_gemm_embed<<<512, 256, 0, stream>>>(Xs, Xq, Wt, emb, rowssq);
  k_proto_partial<<<dim3(PBLK, 8), 256, 0, stream>>>(emb, rowssq, labels, Ppart);
  k_proto_reduce<<<NC * ED / 256, 256, 0, stream>>>(Ppart, Pbf);
  k_scores<<<NQ / 16, 64, 0, stream>>>(emb + (size_t)NS * ED, rowssq + NS, Pbf, out);
}